// Round 5
// baseline (12328.875 us; speedup 1.0000x reference)
//
#include <hip/hip_runtime.h>
#include <math.h>

#define NT 576

__device__ __forceinline__ float sigf(float x){ return 1.0f/(1.0f+expf(-x)); }

__launch_bounds__(NT, 1)
__global__ void kf_fwd(const float* __restrict__ a_seq, const float* __restrict__ h_obs,
  const float* __restrict__ Amat, const float* __restrict__ Cmat, const float* __restrict__ Bmat,
  const float* __restrict__ u_seq, const float* __restrict__ mask, const float* __restrict__ P0,
  const float* __restrict__ matQ, const float* __restrict__ matR,
  const float* __restrict__ Wx, const float* __restrict__ Wh, const float* __restrict__ gbias,
  const float* __restrict__ outW, const float* __restrict__ outb, float* __restrict__ out)
{
  constexpr int T=256, B=128;
  constexpr int L6=36, L0=20;
  constexpr size_t BT=(size_t)B*T;
  const size_t off_zf=0;
  const size_t off_Pf=off_zf+BT*32;
  const size_t off_zl=off_Pf+BT*1024;
  const size_t off_tr=off_zl+BT*32;
  const size_t off_zp=off_tr+BT*1024;
  const size_t off_Pp=off_zp+BT*32;
  const size_t off_af=off_Pp+BT*1024;
  const size_t off_ap=off_af+BT*16;
  const size_t off_S =off_ap+BT*16;
  const size_t off_al=off_S +BT*256;
  const size_t off_ai=off_al+BT*8;
  const size_t off_R =off_ai+BT*8;
  const size_t off_Q =off_R +256;

  // LDS-resident small weights
  __shared__ __align__(16) float sA[8*32*L6];
  __shared__ __align__(16) float sC[8*16*L6];
  __shared__ __align__(16) float sCA[8*16*L6];   // CA_k = C_k @ A_k
  __shared__ __align__(16) float sBm[1024];
  __shared__ __align__(16) float souWT[512];     // [r][q] = outW[q*8+r]
  __shared__ __align__(16) float sgb[192];
  __shared__ __align__(16) float soutb[8];
  // work matrices
  __shared__ __align__(16) float P[32*L6], Ak[32*L6], AkT[32*L6], IKCm[32*L6], IKCT[32*L6];
  __shared__ __align__(16) float T1[32*L6], T3[32*L6], Qm[32*L6], sTril[32*L6];
  __shared__ __align__(16) float Ck[16*L6], CPm[16*L6], KgT[16*L6];
  __shared__ __align__(16) float CPT[32*L0], Kg[32*L0], KgR[32*L0];
  __shared__ __align__(16) float Sm[16*L0], Rm[16*L0], Sinv[16*L0];
  __shared__ __align__(16) float Linv[16*17];
  __shared__ __align__(16) float Bk[128];
  __shared__ __align__(16) float zj[256], aj[128];
  __shared__ __align__(16) float gxp[384], ghlv[192], xin[192];
  __shared__ __align__(16) float zc[32], znew[32], zloc[32], zpred[32], ghs[64];
  __shared__ __align__(16) float ak[16], uk[4], rk[16], ll[8], alpha8[8];
  __shared__ float mval;

  const int tid = threadIdx.x;
  const int b = blockIdx.x;

  // ---------- weights into registers ----------
  // threads 0-191:  Wx rows 0-95,  column c=tid
  // threads 192-383: Wx rows 96-191, column c=tid-192
  // threads 384-575: Wh rows 0-63, column c=tid-384
  float wreg[96];
  if (tid<384){
    int hcol=(tid>=192); int c=tid-hcol*192;
    const float* wp=Wx+(size_t)(hcol*96)*192+c;
    #pragma unroll
    for (int i=0;i<96;i++) wreg[i]=wp[(size_t)i*192];
  } else {
    int c=tid-384;
    const float* wp=Wh+c;
    #pragma unroll
    for (int i=0;i<64;i++) wreg[i]=wp[(size_t)i*192];
  }

  // ---------- stage LDS ----------
  for (int e=tid; e<8192; e+=NT){ int k=e>>10, i=(e>>5)&31, j=e&31; sA[(k*32+i)*L6+j]=Amat[e]; }
  for (int e=tid; e<4096; e+=NT){ int k=e>>9, a=(e>>5)&15, i=e&31; sC[(k*16+a)*L6+i]=Cmat[e]; }
  for (int e=tid; e<1024; e+=NT) sBm[e]=Bmat[e];
  if (tid<512){ int r=tid>>6, q=tid&63; souWT[r*64+q]=outW[q*8+r]; }
  if (tid<192) sgb[tid]=gbias[tid];
  if (tid<8)   soutb[tid]=outb[tid];
  for (int e=tid; e<1024; e+=NT){
    int i=e>>5, j=e&31;
    float s=0.f;
    #pragma unroll
    for (int k=0;k<32;k++) s += matQ[i*32+k]*matQ[j*32+k];
    Qm[i*L6+j]=s+(i==j?0.001f:0.f);
    P[i*L6+j]=P0[e];
  }
  for (int e=tid; e<256; e+=NT){
    int i=e>>4, j=e&15;
    float s=0.f;
    #pragma unroll
    for (int k=0;k<16;k++) s += matR[i*16+k]*matR[j*16+k];
    Rm[i*L0+j]=s+(i==j?0.001f:0.f);
  }
  for (int e=tid; e<16*L6; e+=NT) Ck[e]=0.f;   // t=0: aprev = 0 (z_prev=0)
  if (tid<32) zc[tid]=0.f;
  if (tid<64) ghs[tid]=0.f;
  if (tid<16) xin[16+tid]=h_obs[b*16+tid];
  __syncthreads();

  // CA_k = C_k @ A_k (one-time) ; R/Q outputs
  for (int e=tid; e<4096; e+=NT){
    int k=e>>9, a=(e>>5)&15, j=e&31;
    float s=0.f;
    #pragma unroll
    for (int i=0;i<32;i++) s += sC[(k*16+a)*L6+i]*sA[(k*32+i)*L6+j];
    sCA[(k*16+a)*L6+j]=s;
  }
  if (b==0){
    for (int e=tid;e<256;e+=NT) out[off_R+e]=Rm[(e>>4)*L0+(e&15)];
    for (int e=tid;e<1024;e+=NT) out[off_Q+e]=Qm[(e>>5)*L6+(e&31)];
  }
  __syncthreads();

  for (int t=0;t<T;t++){
    const size_t bt=(size_t)b*T+t;

    // ==== A: aj=CA_k@zc | zj=A_k@zc | ghl (regs) | aprev | loads | lagged tril/a_pred ====
    if (tid<128){
      int k=tid>>4, a2=tid&15;
      const float* car=&sCA[(k*16+a2)*L6];
      float s0=0.f,s1=0.f,s2=0.f,s3=0.f;
      #pragma unroll
      for (int q=0;q<8;q++){
        float4 cv=*(const float4*)&car[q*4];
        float4 zv=*(const float4*)&zc[q*4];
        s0+=cv.x*zv.x; s1+=cv.y*zv.y; s2+=cv.z*zv.z; s3+=cv.w*zv.w;
      }
      float s=(s0+s1)+(s2+s3);
      aj[tid]=s; xin[64+tid]=s;
    } else if (tid<384){
      int e=tid-128; int k=e>>5, i2=e&31;
      const float* ar=&sA[(k*32+i2)*L6];
      float s0=0.f,s1=0.f,s2=0.f,s3=0.f;
      #pragma unroll
      for (int q=0;q<8;q++){
        float4 av=*(const float4*)&ar[q*4];
        float4 zv=*(const float4*)&zc[q*4];
        s0+=av.x*zv.x; s1+=av.y*zv.y; s2+=av.z*zv.z; s3+=av.w*zv.w;
      }
      zj[e]=(s0+s1)+(s2+s3);
      if (tid<144) ak[tid-128]=a_seq[bt*16+(tid-128)];
      else if (tid<148) uk[tid-144]=u_seq[bt*4+(tid-144)];
      else if (tid==148) mval=mask[bt];
      else if (tid>=160 && tid<176){
        int a2=tid-160;
        float p0=0.f,p1=0.f,p2=0.f,p3=0.f;
        #pragma unroll
        for (int q=0;q<8;q++){
          float4 cv=*(const float4*)&Ck[a2*L6+q*4];
          float4 zv=*(const float4*)&zc[q*4];
          p0+=cv.x*zv.x; p1+=cv.y*zv.y; p2+=cv.z*zv.z; p3+=cv.w*zv.w;
        }
        xin[a2]=(p0+p1)+(p2+p3);
      }
      else if (tid>=176 && tid<208) xin[32+(tid-176)]=zc[tid-176];
      else if (tid>=208 && tid<272){
        if (t>0){
          for (int e4=tid-208; e4<256; e4+=64){
            float4 v=*(const float4*)&sTril[(e4>>3)*L6+(e4&7)*4];
            *(float4*)&out[off_tr+(bt-1)*1024+e4*4]=v;
          }
        }
      }
      else if (tid>=272 && tid<288){
        if (t>0){
          int a2=tid-272;
          float p0=0.f,p1=0.f,p2=0.f,p3=0.f;
          #pragma unroll
          for (int q=0;q<8;q++){
            float4 cv=*(const float4*)&Ck[a2*L6+q*4];
            float4 zv=*(const float4*)&zpred[q*4];
            p0+=cv.x*zv.x; p1+=cv.y*zv.y; p2+=cv.z*zv.z; p3+=cv.w*zv.w;
          }
          out[off_ap+(bt-1)*16+a2]=(p0+p1)+(p2+p3);
        }
      }
    } else {
      int c=tid-384;
      float s0=0.f,s1=0.f,s2=0.f,s3=0.f;
      #pragma unroll
      for (int q=0;q<16;q++){
        float4 gv=*(const float4*)&ghs[q*4];
        s0+=gv.x*wreg[q*4+0]; s1+=gv.y*wreg[q*4+1]; s2+=gv.z*wreg[q*4+2]; s3+=gv.w*wreg[q*4+3];
      }
      ghlv[c]=(s0+s1)+(s2+s3);
    }
    __syncthreads();

    // ==== B: gx = xin @ Wx (register halves) | ll + alpha_imm ====
    if (tid<384){
      int h=(tid>=192); int c=tid-h*192;
      const int xb=h*96;
      float s0=0.f,s1=0.f,s2=0.f,s3=0.f;
      #pragma unroll
      for (int q=0;q<24;q++){
        float4 xv=*(const float4*)&xin[xb+q*4];
        s0+=xv.x*wreg[q*4+0]; s1+=xv.y*wreg[q*4+1]; s2+=xv.z*wreg[q*4+2]; s3+=xv.w*wreg[q*4+3];
      }
      gxp[h*192+c]=(s0+s1)+(s2+s3);
    } else if (tid<392){
      int k=tid-384;
      float s=0.f;
      #pragma unroll
      for (int a=0;a<16;a++){ float d=ak[a]-aj[k*16+a]; s+=d*d; }
      ll[k]=-s;
      float m8=ll[0];
      #pragma unroll
      for (int j=1;j<8;j++) m8=fmaxf(m8,ll[j]);
      float ssum=0.f, ek=0.f;
      #pragma unroll
      for (int j=0;j<8;j++){ float e2=expf(ll[j]-m8); ssum+=e2; if(j==k) ek=e2; }
      out[off_ai+bt*8+k]=ek/ssum*mval;
    }
    __syncthreads();

    // ==== C (wave0): gates -> gh -> logits -> alpha ====
    if (tid<64){
      int j=tid;
      float gr=sgb[j]    +gxp[j]    +gxp[192+j]+ghlv[j];
      float gz=sgb[64+j] +gxp[64+j] +gxp[256+j]+ghlv[64+j];
      float r =sigf(gr);
      float zg=sigf(gz);
      float n =tanhf(sgb[128+j]+gxp[128+j]+gxp[320+j]+r*ghlv[128+j]);
      ghs[j]=(1.f-zg)*n+zg*ghs[j];
      if (tid<8){
        float s0=soutb[tid],s1=0.f,s2=0.f,s3=0.f;
        #pragma unroll
        for (int q=0;q<16;q++){
          float4 g=*(const float4*)&ghs[q*4];
          float4 w=*(const float4*)&souWT[tid*64+q*4];
          s0+=g.x*w.x; s1+=g.y*w.y; s2+=g.z*w.z; s3+=g.w*w.w;
        }
        float s=(s0+s1)+(s2+s3);
        float m8=s;
        m8=fmaxf(m8,__shfl_xor(m8,1));
        m8=fmaxf(m8,__shfl_xor(m8,2));
        m8=fmaxf(m8,__shfl_xor(m8,4));
        float e2=expf(s-m8);
        float ss=e2;
        ss+=__shfl_xor(ss,1); ss+=__shfl_xor(ss,2); ss+=__shfl_xor(ss,4);
        float av=e2/ss;
        alpha8[tid]=av;
        out[off_al+bt*8+tid]=av;
      }
    }
    __syncthreads();

    // ==== H: blends Ak(+AkT), Ck, Bk | znew = blend(zj) ====
    if (tid<256){
      int i=tid>>3, j0=(tid&7)*4;
      float c0=0.f,c1=0.f,c2=0.f,c3=0.f;
      #pragma unroll
      for (int k=0;k<8;k++){
        float al=alpha8[k];
        float4 av=*(const float4*)&sA[(k*32+i)*L6+j0];
        c0+=al*av.x; c1+=al*av.y; c2+=al*av.z; c3+=al*av.w;
      }
      *(float4*)&Ak[i*L6+j0]=make_float4(c0,c1,c2,c3);
      AkT[(j0+0)*L6+i]=c0; AkT[(j0+1)*L6+i]=c1; AkT[(j0+2)*L6+i]=c2; AkT[(j0+3)*L6+i]=c3;
    } else if (tid<384){
      int th=tid-256; int a=th>>3, i0=(th&7)*4;
      float c0=0.f,c1=0.f,c2=0.f,c3=0.f;
      #pragma unroll
      for (int k=0;k<8;k++){
        float al=alpha8[k];
        float4 cv=*(const float4*)&sC[(k*16+a)*L6+i0];
        c0+=al*cv.x; c1+=al*cv.y; c2+=al*cv.z; c3+=al*cv.w;
      }
      *(float4*)&Ck[a*L6+i0]=make_float4(c0,c1,c2,c3);
    } else if (tid<512){
      int e=tid-384;
      float s=0.f;
      #pragma unroll
      for (int k=0;k<8;k++) s+=alpha8[k]*sBm[k*128+e];
      Bk[e]=s;
    } else if (tid<544){
      int i=tid-512;
      float s=0.f;
      #pragma unroll
      for (int k=0;k<8;k++) s+=alpha8[k]*zj[k*32+i];
      znew[i]=s;
    }
    __syncthreads();

    // ==== I: CP = Ck@P (+CPT) | rk = ak - Ck@znew ====
    if (tid<128){
      int a=tid>>3, i0=(tid&7)*4;
      float c0=0.f,c1=0.f,c2=0.f,c3=0.f;
      #pragma unroll
      for (int q=0;q<8;q++){
        float4 ck=*(const float4*)&Ck[a*L6+q*4];
        float4 p0=*(const float4*)&P[(q*4+0)*L6+i0];
        float4 p1=*(const float4*)&P[(q*4+1)*L6+i0];
        float4 p2=*(const float4*)&P[(q*4+2)*L6+i0];
        float4 p3=*(const float4*)&P[(q*4+3)*L6+i0];
        c0+=ck.x*p0.x+ck.y*p1.x+ck.z*p2.x+ck.w*p3.x;
        c1+=ck.x*p0.y+ck.y*p1.y+ck.z*p2.y+ck.w*p3.y;
        c2+=ck.x*p0.z+ck.y*p1.z+ck.z*p2.z+ck.w*p3.z;
        c3+=ck.x*p0.w+ck.y*p1.w+ck.z*p2.w+ck.w*p3.w;
      }
      *(float4*)&CPm[a*L6+i0]=make_float4(c0,c1,c2,c3);
      CPT[(i0+0)*L0+a]=c0; CPT[(i0+1)*L0+a]=c1; CPT[(i0+2)*L0+a]=c2; CPT[(i0+3)*L0+a]=c3;
    } else if (tid<144){
      int a=tid-128;
      float p0=0.f,p1=0.f,p2=0.f,p3=0.f;
      #pragma unroll
      for (int q=0;q<8;q++){
        float4 cv=*(const float4*)&Ck[a*L6+q*4];
        float4 zv=*(const float4*)&znew[q*4];
        p0+=cv.x*zv.x; p1+=cv.y*zv.y; p2+=cv.z*zv.z; p3+=cv.w*zv.w;
      }
      rk[a]=ak[a]-((p0+p1)+(p2+p3));
    }
    __syncthreads();

    // ==== JK (wave0): S = CP@Ck^T + R + 1e-4I -> chol16 -> Linv -> Sinv ====
    if (tid<64){
      int lane=tid;
      {
        int a=lane>>2, c0i=(lane&3)*4;
        float r0=0.f,r1=0.f,r2=0.f,r3=0.f;
        #pragma unroll
        for (int q=0;q<8;q++){
          float4 cp=*(const float4*)&CPm[a*L6+q*4];
          float4 v0=*(const float4*)&Ck[(c0i+0)*L6+q*4];
          float4 v1=*(const float4*)&Ck[(c0i+1)*L6+q*4];
          float4 v2=*(const float4*)&Ck[(c0i+2)*L6+q*4];
          float4 v3=*(const float4*)&Ck[(c0i+3)*L6+q*4];
          r0+=cp.x*v0.x+cp.y*v0.y+cp.z*v0.z+cp.w*v0.w;
          r1+=cp.x*v1.x+cp.y*v1.y+cp.z*v1.z+cp.w*v1.w;
          r2+=cp.x*v2.x+cp.y*v2.y+cp.z*v2.z+cp.w*v2.w;
          r3+=cp.x*v3.x+cp.y*v3.y+cp.z*v3.z+cp.w*v3.w;
        }
        float4 rm=*(const float4*)&Rm[a*L0+c0i];
        r0+=rm.x+((a==c0i+0)?1e-4f:0.f);
        r1+=rm.y+((a==c0i+1)?1e-4f:0.f);
        r2+=rm.z+((a==c0i+2)?1e-4f:0.f);
        r3+=rm.w+((a==c0i+3)?1e-4f:0.f);
        *(float4*)&Sm[a*L0+c0i]=make_float4(r0,r1,r2,r3);
      }
      int row=lane<16?lane:15;
      float Sr[16], Lr[16];
      #pragma unroll
      for (int q=0;q<4;q++){
        float4 v=*(const float4*)&Sm[row*L0+q*4];
        Sr[q*4+0]=v.x; Sr[q*4+1]=v.y; Sr[q*4+2]=v.z; Sr[q*4+3]=v.w;
      }
      #pragma unroll
      for (int c=0;c<16;c++){
        float v=Sr[c];
        #pragma unroll
        for (int k=0;k<c;k++) v-=Lr[k]*__shfl(Lr[k],c);
        float d=__shfl(v,c);
        float inv=rsqrtf(d);
        Lr[c]=(lane==c)?d*inv:v*inv;
      }
      float Li[16];
      #pragma unroll
      for (int r=0;r<16;r++){
        float tv=(lane==r)?1.f:0.f;
        #pragma unroll
        for (int k=0;k<r;k++) tv-=__shfl(Lr[k],r)*Li[k];
        Li[r]=tv/__shfl(Lr[r],r);
      }
      if (lane<16){
        #pragma unroll
        for (int r=0;r<16;r++) Linv[r*17+lane]=Li[r];
      }
      #pragma unroll
      for (int q=0;q<4;q++){
        int e=lane+64*q; int a2=e>>4, b2=e&15;
        float s=0.f;
        #pragma unroll
        for (int k=0;k<16;k++) s+=Linv[k*17+a2]*Linv[k*17+b2];
        Sinv[a2*L0+b2]=s;
      }
    }
    __syncthreads();

    // ==== M: Kg = CPT@Sinv * mval (+KgT) | S store ====
    if (tid<128){
      int i=tid>>2, a0=(tid&3)*4;
      float c0=0.f,c1=0.f,c2=0.f,c3=0.f;
      #pragma unroll
      for (int q=0;q<4;q++){
        float4 cp=*(const float4*)&CPT[i*L0+q*4];
        float4 s0=*(const float4*)&Sinv[(q*4+0)*L0+a0];
        float4 s1=*(const float4*)&Sinv[(q*4+1)*L0+a0];
        float4 s2=*(const float4*)&Sinv[(q*4+2)*L0+a0];
        float4 s3=*(const float4*)&Sinv[(q*4+3)*L0+a0];
        c0+=cp.x*s0.x+cp.y*s1.x+cp.z*s2.x+cp.w*s3.x;
        c1+=cp.x*s0.y+cp.y*s1.y+cp.z*s2.y+cp.w*s3.y;
        c2+=cp.x*s0.z+cp.y*s1.z+cp.z*s2.z+cp.w*s3.z;
        c3+=cp.x*s0.w+cp.y*s1.w+cp.z*s2.w+cp.w*s3.w;
      }
      float m=mval;
      c0*=m; c1*=m; c2*=m; c3*=m;
      *(float4*)&Kg[i*L0+a0]=make_float4(c0,c1,c2,c3);
      KgT[(a0+0)*L6+i]=c0; KgT[(a0+1)*L6+i]=c1; KgT[(a0+2)*L6+i]=c2; KgT[(a0+3)*L6+i]=c3;
    } else if (tid<192){
      int th=tid-128;
      float4 v=*(const float4*)&Sm[(th>>2)*L0+(th&3)*4];
      *(float4*)&out[off_S+bt*256+th*4]=v;
    }
    __syncthreads();

    // ==== N: IKC (+IKCT) | KgR | zloc ====
    if (tid<256){
      int i=tid>>3, j0=(tid&7)*4;
      float c0=(i==j0+0)?1.f:0.f;
      float c1=(i==j0+1)?1.f:0.f;
      float c2=(i==j0+2)?1.f:0.f;
      float c3=(i==j0+3)?1.f:0.f;
      #pragma unroll
      for (int q=0;q<4;q++){
        float4 kg=*(const float4*)&Kg[i*L0+q*4];
        float4 v0=*(const float4*)&Ck[(q*4+0)*L6+j0];
        float4 v1=*(const float4*)&Ck[(q*4+1)*L6+j0];
        float4 v2=*(const float4*)&Ck[(q*4+2)*L6+j0];
        float4 v3=*(const float4*)&Ck[(q*4+3)*L6+j0];
        c0-=kg.x*v0.x+kg.y*v1.x+kg.z*v2.x+kg.w*v3.x;
        c1-=kg.x*v0.y+kg.y*v1.y+kg.z*v2.y+kg.w*v3.y;
        c2-=kg.x*v0.z+kg.y*v1.z+kg.z*v2.z+kg.w*v3.z;
        c3-=kg.x*v0.w+kg.y*v1.w+kg.z*v2.w+kg.w*v3.w;
      }
      *(float4*)&IKCm[i*L6+j0]=make_float4(c0,c1,c2,c3);
      IKCT[(j0+0)*L6+i]=c0; IKCT[(j0+1)*L6+i]=c1; IKCT[(j0+2)*L6+i]=c2; IKCT[(j0+3)*L6+i]=c3;
    } else if (tid<384){
      int th=tid-256; int i=th>>2, a0=(th&3)*4;
      float c0=0.f,c1=0.f,c2=0.f,c3=0.f;
      #pragma unroll
      for (int q=0;q<4;q++){
        float4 kg=*(const float4*)&Kg[i*L0+q*4];
        float4 v0=*(const float4*)&Rm[(q*4+0)*L0+a0];
        float4 v1=*(const float4*)&Rm[(q*4+1)*L0+a0];
        float4 v2=*(const float4*)&Rm[(q*4+2)*L0+a0];
        float4 v3=*(const float4*)&Rm[(q*4+3)*L0+a0];
        c0+=kg.x*v0.x+kg.y*v1.x+kg.z*v2.x+kg.w*v3.x;
        c1+=kg.x*v0.y+kg.y*v1.y+kg.z*v2.y+kg.w*v3.y;
        c2+=kg.x*v0.z+kg.y*v1.z+kg.z*v2.z+kg.w*v3.z;
        c3+=kg.x*v0.w+kg.y*v1.w+kg.z*v2.w+kg.w*v3.w;
      }
      *(float4*)&KgR[i*L0+a0]=make_float4(c0,c1,c2,c3);
    } else if (tid<416){
      int i=tid-384;
      float s=znew[i];
      #pragma unroll
      for (int a=0;a<16;a++) s+=Kg[i*L0+a]*rk[a];
      zloc[i]=s;
    }
    __syncthreads();

    // ==== OP: T1=IKC@P ; T3=T1@IKCT+KgR@KgT+.001I | zf/zl/zp/af | zc carry ====
    if (tid<128){
      int i0=(tid>>3)*2, j0=(tid&7)*4;
      float a00=0.f,a01=0.f,a02=0.f,a03=0.f,a10=0.f,a11=0.f,a12=0.f,a13=0.f;
      #pragma unroll
      for (int q=0;q<8;q++){
        float4 wa=*(const float4*)&IKCm[i0*L6+q*4];
        float4 wb=*(const float4*)&IKCm[(i0+1)*L6+q*4];
        float4 p0=*(const float4*)&P[(q*4+0)*L6+j0];
        float4 p1=*(const float4*)&P[(q*4+1)*L6+j0];
        float4 p2=*(const float4*)&P[(q*4+2)*L6+j0];
        float4 p3=*(const float4*)&P[(q*4+3)*L6+j0];
        a00+=wa.x*p0.x+wa.y*p1.x+wa.z*p2.x+wa.w*p3.x;
        a01+=wa.x*p0.y+wa.y*p1.y+wa.z*p2.y+wa.w*p3.y;
        a02+=wa.x*p0.z+wa.y*p1.z+wa.z*p2.z+wa.w*p3.z;
        a03+=wa.x*p0.w+wa.y*p1.w+wa.z*p2.w+wa.w*p3.w;
        a10+=wb.x*p0.x+wb.y*p1.x+wb.z*p2.x+wb.w*p3.x;
        a11+=wb.x*p0.y+wb.y*p1.y+wb.z*p2.y+wb.w*p3.y;
        a12+=wb.x*p0.z+wb.y*p1.z+wb.z*p2.z+wb.w*p3.z;
        a13+=wb.x*p0.w+wb.y*p1.w+wb.z*p2.w+wb.w*p3.w;
      }
      *(float4*)&T1[i0*L6+j0]=make_float4(a00,a01,a02,a03);
      *(float4*)&T1[(i0+1)*L6+j0]=make_float4(a10,a11,a12,a13);
      // T3 = T1@IKCT + KgR@KgT  (T1 rows completed by this same wave)
      a00=0.f;a01=0.f;a02=0.f;a03=0.f;a10=0.f;a11=0.f;a12=0.f;a13=0.f;
      #pragma unroll
      for (int q=0;q<8;q++){
        float4 wa=*(const float4*)&T1[i0*L6+q*4];
        float4 wb=*(const float4*)&T1[(i0+1)*L6+q*4];
        float4 v0=*(const float4*)&IKCT[(q*4+0)*L6+j0];
        float4 v1=*(const float4*)&IKCT[(q*4+1)*L6+j0];
        float4 v2=*(const float4*)&IKCT[(q*4+2)*L6+j0];
        float4 v3=*(const float4*)&IKCT[(q*4+3)*L6+j0];
        a00+=wa.x*v0.x+wa.y*v1.x+wa.z*v2.x+wa.w*v3.x;
        a01+=wa.x*v0.y+wa.y*v1.y+wa.z*v2.y+wa.w*v3.y;
        a02+=wa.x*v0.z+wa.y*v1.z+wa.z*v2.z+wa.w*v3.z;
        a03+=wa.x*v0.w+wa.y*v1.w+wa.z*v2.w+wa.w*v3.w;
        a10+=wb.x*v0.x+wb.y*v1.x+wb.z*v2.x+wb.w*v3.x;
        a11+=wb.x*v0.y+wb.y*v1.y+wb.z*v2.y+wb.w*v3.y;
        a12+=wb.x*v0.z+wb.y*v1.z+wb.z*v2.z+wb.w*v3.z;
        a13+=wb.x*v0.w+wb.y*v1.w+wb.z*v2.w+wb.w*v3.w;
      }
      #pragma unroll
      for (int q=0;q<4;q++){
        float4 ka=*(const float4*)&KgR[i0*L0+q*4];
        float4 kb=*(const float4*)&KgR[(i0+1)*L0+q*4];
        float4 v0=*(const float4*)&KgT[(q*4+0)*L6+j0];
        float4 v1=*(const float4*)&KgT[(q*4+1)*L6+j0];
        float4 v2=*(const float4*)&KgT[(q*4+2)*L6+j0];
        float4 v3=*(const float4*)&KgT[(q*4+3)*L6+j0];
        a00+=ka.x*v0.x+ka.y*v1.x+ka.z*v2.x+ka.w*v3.x;
        a01+=ka.x*v0.y+ka.y*v1.y+ka.z*v2.y+ka.w*v3.y;
        a02+=ka.x*v0.z+ka.y*v1.z+ka.z*v2.z+ka.w*v3.z;
        a03+=ka.x*v0.w+ka.y*v1.w+ka.z*v2.w+ka.w*v3.w;
        a10+=kb.x*v0.x+kb.y*v1.x+kb.z*v2.x+kb.w*v3.x;
        a11+=kb.x*v0.y+kb.y*v1.y+kb.z*v2.y+kb.w*v3.y;
        a12+=kb.x*v0.z+kb.y*v1.z+kb.z*v2.z+kb.w*v3.z;
        a13+=kb.x*v0.w+kb.y*v1.w+kb.z*v2.w+kb.w*v3.w;
      }
      float d0[4]={a00,a01,a02,a03}, d1[4]={a10,a11,a12,a13};
      #pragma unroll
      for (int q=0;q<4;q++){
        if (i0==j0+q)   d0[q]+=0.001f;
        if (i0+1==j0+q) d1[q]+=0.001f;
      }
      *(float4*)&T3[i0*L6+j0]=make_float4(d0[0],d0[1],d0[2],d0[3]);
      *(float4*)&T3[(i0+1)*L6+j0]=make_float4(d1[0],d1[1],d1[2],d1[3]);
    } else if (tid<160){
      int row=tid-128;
      float zl=zloc[row];
      out[off_zf+bt*32+row]=zl;
      out[off_zl+bt*32+row]=zl;
    } else if (tid<192){
      int i=tid-160;
      float s0=0.f,s1=0.f,s2=0.f,s3=0.f;
      #pragma unroll
      for (int q=0;q<8;q++){
        float4 av=*(const float4*)&Ak[i*L6+q*4];
        float4 zv=*(const float4*)&zloc[q*4];
        s0+=av.x*zv.x; s1+=av.y*zv.y; s2+=av.z*zv.z; s3+=av.w*zv.w;
      }
      float s=(s0+s1)+(s2+s3);
      s+=Bk[i*4+0]*uk[0]+Bk[i*4+1]*uk[1]+Bk[i*4+2]*uk[2]+Bk[i*4+3]*uk[3];
      zpred[i]=s;
      out[off_zp+bt*32+i]=s;
    } else if (tid<208){
      int a=tid-192;
      float s0=0.f,s1=0.f,s2=0.f,s3=0.f;
      #pragma unroll
      for (int q=0;q<8;q++){
        float4 cv=*(const float4*)&Ck[a*L6+q*4];
        float4 zv=*(const float4*)&zloc[q*4];
        s0+=cv.x*zv.x; s1+=cv.y*zv.y; s2+=cv.z*zv.z; s3+=cv.w*zv.w;
      }
      out[off_af+bt*16+a]=(s0+s1)+(s2+s3);
    } else if (tid<240){
      int i=tid-208;
      zc[i]=zloc[i];
    }
    __syncthreads();

    // ==== R: chol32(T3)->sTril (wave0) | Pp=Ak@T3@AkT+Q->P (waves1-2) | Pf store (wave3) ====
    {
      int wv=tid>>6, lane=tid&63;
      if (wv==0){
        int row=lane<32?lane:31;
        float Pr[32], Lr[32];
        #pragma unroll
        for (int q=0;q<8;q++){
          float4 v=*(const float4*)&T3[row*L6+q*4];
          Pr[q*4+0]=v.x; Pr[q*4+1]=v.y; Pr[q*4+2]=v.z; Pr[q*4+3]=v.w;
        }
        #pragma unroll
        for (int c=0;c<32;c++){
          float v=Pr[c];
          #pragma unroll
          for (int k=0;k<c;k++) v-=Lr[k]*__shfl(Lr[k],c);
          float d=__shfl(v,c);
          float inv=rsqrtf(d);
          Lr[c]=(lane==c)?d*inv:v*inv;
        }
        if (lane<32){
          #pragma unroll
          for (int q=0;q<8;q++){
            float t0=(q*4+0<=lane)?Lr[q*4+0]:0.f;
            float t1=(q*4+1<=lane)?Lr[q*4+1]:0.f;
            float t2=(q*4+2<=lane)?Lr[q*4+2]:0.f;
            float t3=(q*4+3<=lane)?Lr[q*4+3]:0.f;
            *(float4*)&sTril[lane*L6+q*4]=make_float4(t0,t1,t2,t3);
          }
        }
      } else if (wv<3){
        int th=tid-64;
        int i0=(th>>3)*2, j0=(th&7)*4;
        float a00=0.f,a01=0.f,a02=0.f,a03=0.f,a10=0.f,a11=0.f,a12=0.f,a13=0.f;
        #pragma unroll
        for (int q=0;q<8;q++){
          float4 wa=*(const float4*)&Ak[i0*L6+q*4];
          float4 wb=*(const float4*)&Ak[(i0+1)*L6+q*4];
          float4 p0=*(const float4*)&T3[(q*4+0)*L6+j0];
          float4 p1=*(const float4*)&T3[(q*4+1)*L6+j0];
          float4 p2=*(const float4*)&T3[(q*4+2)*L6+j0];
          float4 p3=*(const float4*)&T3[(q*4+3)*L6+j0];
          a00+=wa.x*p0.x+wa.y*p1.x+wa.z*p2.x+wa.w*p3.x;
          a01+=wa.x*p0.y+wa.y*p1.y+wa.z*p2.y+wa.w*p3.y;
          a02+=wa.x*p0.z+wa.y*p1.z+wa.z*p2.z+wa.w*p3.z;
          a03+=wa.x*p0.w+wa.y*p1.w+wa.z*p2.w+wa.w*p3.w;
          a10+=wb.x*p0.x+wb.y*p1.x+wb.z*p2.x+wb.w*p3.x;
          a11+=wb.x*p0.y+wb.y*p1.y+wb.z*p2.y+wb.w*p3.y;
          a12+=wb.x*p0.z+wb.y*p1.z+wb.z*p2.z+wb.w*p3.z;
          a13+=wb.x*p0.w+wb.y*p1.w+wb.z*p2.w+wb.w*p3.w;
        }
        *(float4*)&T1[i0*L6+j0]=make_float4(a00,a01,a02,a03);
        *(float4*)&T1[(i0+1)*L6+j0]=make_float4(a10,a11,a12,a13);
        float4 q0v=*(const float4*)&Qm[i0*L6+j0];
        float4 q1v=*(const float4*)&Qm[(i0+1)*L6+j0];
        float d0[4]={q0v.x,q0v.y,q0v.z,q0v.w}, d1[4]={q1v.x,q1v.y,q1v.z,q1v.w};
        #pragma unroll
        for (int q=0;q<4;q++){
          if (i0==j0+q)   d0[q]+=0.001f;
          if (i0+1==j0+q) d1[q]+=0.001f;
        }
        #pragma unroll
        for (int q=0;q<8;q++){
          float4 wa=*(const float4*)&T1[i0*L6+q*4];
          float4 wb=*(const float4*)&T1[(i0+1)*L6+q*4];
          float4 v0=*(const float4*)&AkT[(q*4+0)*L6+j0];
          float4 v1=*(const float4*)&AkT[(q*4+1)*L6+j0];
          float4 v2=*(const float4*)&AkT[(q*4+2)*L6+j0];
          float4 v3=*(const float4*)&AkT[(q*4+3)*L6+j0];
          d0[0]+=wa.x*v0.x+wa.y*v1.x+wa.z*v2.x+wa.w*v3.x;
          d0[1]+=wa.x*v0.y+wa.y*v1.y+wa.z*v2.y+wa.w*v3.y;
          d0[2]+=wa.x*v0.z+wa.y*v1.z+wa.z*v2.z+wa.w*v3.z;
          d0[3]+=wa.x*v0.w+wa.y*v1.w+wa.z*v2.w+wa.w*v3.w;
          d1[0]+=wb.x*v0.x+wb.y*v1.x+wb.z*v2.x+wb.w*v3.x;
          d1[1]+=wb.x*v0.y+wb.y*v1.y+wb.z*v2.y+wb.w*v3.y;
          d1[2]+=wb.x*v0.z+wb.y*v1.z+wb.z*v2.z+wb.w*v3.z;
          d1[3]+=wb.x*v0.w+wb.y*v1.w+wb.z*v2.w+wb.w*v3.w;
        }
        float4 p0=make_float4(d0[0],d0[1],d0[2],d0[3]);
        float4 p1=make_float4(d1[0],d1[1],d1[2],d1[3]);
        *(float4*)&P[i0*L6+j0]=p0;
        *(float4*)&P[(i0+1)*L6+j0]=p1;
        *(float4*)&out[off_Pp+bt*1024+i0*32+j0]=p0;
        *(float4*)&out[off_Pp+bt*1024+(i0+1)*32+j0]=p1;
      } else if (wv==3 && lane<32){
        int row=lane;
        #pragma unroll
        for (int q=0;q<8;q++){
          float4 v=*(const float4*)&T3[row*L6+q*4];
          *(float4*)&out[off_Pf+bt*1024+row*32+q*4]=v;
        }
      }
    }
    __syncthreads();
  }

  // epilogue: tril and a_pred for t = T-1
  {
    const size_t btL=(size_t)b*T+(T-1);
    for (int e4=tid; e4<256; e4+=NT){
      float4 v=*(const float4*)&sTril[(e4>>3)*L6+(e4&7)*4];
      *(float4*)&out[off_tr+btL*1024+e4*4]=v;
    }
    if (tid<16){
      float s0=0.f,s1=0.f,s2=0.f,s3=0.f;
      #pragma unroll
      for (int q=0;q<8;q++){
        float4 cv=*(const float4*)&Ck[tid*L6+q*4];
        float4 zv=*(const float4*)&zpred[q*4];
        s0+=cv.x*zv.x; s1+=cv.y*zv.y; s2+=cv.z*zv.z; s3+=cv.w*zv.w;
      }
      out[off_ap+btL*16+tid]=(s0+s1)+(s2+s3);
    }
  }
}

extern "C" void kernel_launch(void* const* d_in, const int* in_sizes, int n_in,
                              void* d_out, int out_size, void* d_ws, size_t ws_size,
                              hipStream_t stream) {
  kf_fwd<<<128, NT, 0, stream>>>(
    (const float*)d_in[0],  // a_seq
    (const float*)d_in[1],  // h_obs
    (const float*)d_in[2],  // A_matrices
    (const float*)d_in[3],  // C_matrices
    (const float*)d_in[4],  // B_matrices
    (const float*)d_in[5],  // u_seq
    (const float*)d_in[6],  // mask
    (const float*)d_in[7],  // P_0
    (const float*)d_in[8],  // mat_Q
    (const float*)d_in[9],  // mat_R
    (const float*)d_in[10], // gru_Wx
    (const float*)d_in[11], // gru_Wh
    (const float*)d_in[12], // gru_b
    (const float*)d_in[13], // out_W
    (const float*)d_in[14], // out_b
    (float*)d_out);
}